// Round 6
// baseline (1679.154 us; speedup 1.0000x reference)
//
#include <hip/hip_runtime.h>
#include <math.h>

// Problem dims (fixed)
#define S_DIM 4096
#define B_DIM 8
#define E_DIM 1024
#define H_DIM 16
#define HD_DIM 64
#define FF_DIM 4096
#define ROWS (S_DIM * B_DIM)   // 32768 rows of [E]

typedef _Float16 half8 __attribute__((ext_vector_type(8)));
typedef _Float16 half4 __attribute__((ext_vector_type(4)));
typedef float f32x4 __attribute__((ext_vector_type(4)));

#if defined(__has_builtin)
#if __has_builtin(__builtin_amdgcn_global_load_lds)
#define HAVE_GLL 1
#endif
#endif
#ifndef HAVE_GLL
#define HAVE_GLL 0
#endif

#if HAVE_GLL
// Direct global->LDS DMA, 16B per lane. LDS dest = wave-uniform base + lane*16
// (m104/m108): base must be wave-uniform, layout linear in lane order.
__device__ __forceinline__ void gload_lds16(const _Float16* g, _Float16* l) {
    __builtin_amdgcn_global_load_lds(
        (const __attribute__((address_space(1))) unsigned int*)g,
        (__attribute__((address_space(3))) unsigned int*)l,
        16, 0, 0);
}
#endif

// ---------------------------------------------------------------------------
// Weight convert + transpose: W fp32 [K][N] -> Wt f16 [N][K].
// 32x32 LDS tile, 256 threads (32x8), coalesced both sides.
// ---------------------------------------------------------------------------
__global__ __launch_bounds__(256) void cvt_t_kernel(const float* __restrict__ W,
                                                    _Float16* __restrict__ Wt,
                                                    int K, int N) {
    __shared__ float tile[32][33];
    int t = threadIdx.x;
    int x = t & 31, y = t >> 5;             // y in 0..7
    int n0 = blockIdx.x * 32, k0 = blockIdx.y * 32;
    #pragma unroll
    for (int j = 0; j < 4; ++j)
        tile[y + 8 * j][x] = W[(size_t)(k0 + y + 8 * j) * N + n0 + x];
    __syncthreads();
    #pragma unroll
    for (int j = 0; j < 4; ++j)
        Wt[(size_t)(n0 + y + 8 * j) * K + k0 + x] = (_Float16)tile[x][y + 8 * j];
}

// ---------------------------------------------------------------------------
// LayerNorm: one block (256 thr) per row of 1024 fp32; writes f16.
// ---------------------------------------------------------------------------
__global__ __launch_bounds__(256) void ln16_kernel(const float* __restrict__ x,
                                                   const float* __restrict__ g,
                                                   const float* __restrict__ b,
                                                   _Float16* __restrict__ y) {
    int row = blockIdx.x;
    const float* xr = x + (size_t)row * E_DIM;
    _Float16* yr = y + (size_t)row * E_DIM;
    int t = threadIdx.x;
    float4 v = *reinterpret_cast<const float4*>(xr + t * 4);
    float s1 = v.x + v.y + v.z + v.w;
    float s2 = v.x * v.x + v.y * v.y + v.z * v.z + v.w * v.w;
    #pragma unroll
    for (int off = 1; off < 64; off <<= 1) {
        s1 += __shfl_xor(s1, off, 64);
        s2 += __shfl_xor(s2, off, 64);
    }
    __shared__ float red[2][4];
    int wave = t >> 6;
    if ((t & 63) == 0) { red[0][wave] = s1; red[1][wave] = s2; }
    __syncthreads();
    s1 = red[0][0] + red[0][1] + red[0][2] + red[0][3];
    s2 = red[1][0] + red[1][1] + red[1][2] + red[1][3];
    float mean = s1 * (1.0f / E_DIM);
    float var  = s2 * (1.0f / E_DIM) - mean * mean;
    float rstd = rsqrtf(var + 1e-5f);
    float4 gv = *reinterpret_cast<const float4*>(g + t * 4);
    float4 bv = *reinterpret_cast<const float4*>(b + t * 4);
    half4 o;
    o[0] = (_Float16)((v.x - mean) * rstd * gv.x + bv.x);
    o[1] = (_Float16)((v.y - mean) * rstd * gv.y + bv.y);
    o[2] = (_Float16)((v.z - mean) * rstd * gv.z + bv.z);
    o[3] = (_Float16)((v.w - mean) * rstd * gv.w + bv.w);
    *reinterpret_cast<half4*>(yr + t * 4) = o;
}

// ---------------------------------------------------------------------------
// f16 MFMA GEMM (m97 structure): C = epi(A[M,K] @ Wt[N,K]^T + bias) [+ res]
// 128x128 tile, BK=32, 4 waves (2x2), wave = 64x64 = 4x4 frags of 16x16x32.
// Staging via global_load_lds width=16 into LINEAR LDS [128][32] halves:
//   wave w call c stages 1KB at byte (c*4096 + w*1024); lane l -> +l*16.
//   => row = c*64 + w*16 + l/4, col-halves = (l&3)*8; global src per-lane.
// No swizzle/no setprio: T2/T5 are null at 2-phase (m252/m233/m190).
// A-frag: lane holds A[row=l&15][k=8*(l>>4)+j]; B-frag same on Wt rows.
// C/D: col=lane&15, row=(lane>>4)*4+reg  [m89/m91, dtype-indep m121-128].
// XCD swizzle (T1, bijective, nwg%8==0): contiguous tile chunk per XCD.
// ---------------------------------------------------------------------------
#define BK 32

template<int EPI_GELU, int HAS_RES, int OUT_HALF>
__global__ __launch_bounds__(256) void gemm16_kernel(const _Float16* __restrict__ A,
                                                     const _Float16* __restrict__ Bt,
                                                     const float* __restrict__ bias,
                                                     const float* __restrict__ res,
                                                     void* __restrict__ Cout,
                                                     int K, int N) {
    __shared__ __align__(16) _Float16 As[128 * BK];   // 8 KB
    __shared__ __align__(16) _Float16 Bs[128 * BK];   // 8 KB
    int t = threadIdx.x;
    int lane = t & 63;
    int w = t >> 6;
    int wr = w >> 1, wc = w & 1;
    int lr = lane & 15, ks = lane >> 4;

    // XCD-aware block swizzle (nwg % 8 == 0 for all our launches)
    int nwg = gridDim.x * gridDim.y;
    int f = blockIdx.y * gridDim.x + blockIdx.x;
    int lt = (f & 7) * (nwg >> 3) + (f >> 3);
    int bxl = lt % gridDim.x;
    int byl = lt / gridDim.x;
    int brow = byl * 128, bcol = bxl * 128;

    // staging map (shared by both paths): thread t covers rows srow, srow+64
    int srow = w * 16 + (lane >> 2);   // 0..63
    int scol = (lane & 3) * 8;         // halves offset within BK
    const _Float16* Ag0 = A  + (size_t)(brow + srow) * K + scol;
    const _Float16* Ag1 = A  + (size_t)(brow + 64 + srow) * K + scol;
    const _Float16* Bg0 = Bt + (size_t)(bcol + srow) * K + scol;
    const _Float16* Bg1 = Bt + (size_t)(bcol + 64 + srow) * K + scol;
#if HAVE_GLL
    _Float16* ldsA0 = As + w * 512;          // byte w*1024
    _Float16* ldsA1 = As + 2048 + w * 512;   // byte 4096 + w*1024
    _Float16* ldsB0 = Bs + w * 512;
    _Float16* ldsB1 = Bs + 2048 + w * 512;
#else
    _Float16* wA0 = As + srow * BK + scol;
    _Float16* wA1 = As + (srow + 64) * BK + scol;
    _Float16* wB0 = Bs + srow * BK + scol;
    _Float16* wB1 = Bs + (srow + 64) * BK + scol;
#endif

    f32x4 acc[4][4];
    #pragma unroll
    for (int i = 0; i < 4; ++i)
        #pragma unroll
        for (int j = 0; j < 4; ++j)
            acc[i][j] = {0.0f, 0.0f, 0.0f, 0.0f};

    for (int kt = 0; kt < K; kt += BK) {
#if HAVE_GLL
        if (kt) __syncthreads();          // prev tile fully consumed
        gload_lds16(Ag0 + kt, ldsA0);
        gload_lds16(Ag1 + kt, ldsA1);
        gload_lds16(Bg0 + kt, ldsB0);
        gload_lds16(Bg1 + kt, ldsB1);
        __syncthreads();                  // barrier drains vmcnt -> LDS ready
#else
        half8 va0 = *(const half8*)(Ag0 + kt);
        half8 va1 = *(const half8*)(Ag1 + kt);
        half8 vb0 = *(const half8*)(Bg0 + kt);
        half8 vb1 = *(const half8*)(Bg1 + kt);
        __syncthreads();
        *(half8*)wA0 = va0;
        *(half8*)wA1 = va1;
        *(half8*)wB0 = vb0;
        *(half8*)wB1 = vb1;
        __syncthreads();
#endif
        half8 af[4], bf[4];
        #pragma unroll
        for (int i = 0; i < 4; ++i)
            af[i] = *(const half8*)&As[(wr * 64 + i * 16 + lr) * BK + ks * 8];
        #pragma unroll
        for (int j = 0; j < 4; ++j)
            bf[j] = *(const half8*)&Bs[(wc * 64 + j * 16 + lr) * BK + ks * 8];
        #pragma unroll
        for (int i = 0; i < 4; ++i)
            #pragma unroll
            for (int j = 0; j < 4; ++j)
                acc[i][j] = __builtin_amdgcn_mfma_f32_16x16x32_f16(af[i], bf[j], acc[i][j], 0, 0, 0);
    }

    float* Cf = (float*)Cout;
    _Float16* Ch = (_Float16*)Cout;
    int mrow = brow + wr * 64 + (lane >> 4) * 4;
    int ncol = bcol + wc * 64 + lr;
    #pragma unroll
    for (int i = 0; i < 4; ++i) {
        #pragma unroll
        for (int j = 0; j < 4; ++j) {
            int n = ncol + j * 16;
            float bv = bias[n];
            #pragma unroll
            for (int q = 0; q < 4; ++q) {
                int m = mrow + i * 16 + q;
                float v = acc[i][j][q] + bv;
                if (EPI_GELU)
                    v = 0.5f * v * (1.0f + erff(v * 0.70710678118654752f));
                if (HAS_RES)
                    v += res[(size_t)m * N + n];
                if (OUT_HALF) Ch[(size_t)m * N + n] = (_Float16)v;
                else          Cf[(size_t)m * N + n] = v;
            }
        }
    }
}

// ---------------------------------------------------------------------------
// Cross-batch attention (f16 in, f16 out, fp32 math). One wave per (s,h).
// scores[b,c] over batch (B=8). lane=b*8+c; softmax via shfl in 8-lane groups;
// PV: lane=b*8+g owns d=g*8..g*8+7. Z pre-scrambled for the
// transpose(2,0,1,3).reshape(S,B,E): Z[((b*H+h)*S+s)*HD+d].
// ---------------------------------------------------------------------------
__global__ __launch_bounds__(256) void attn16_kernel(const _Float16* __restrict__ Q,
                                                     const _Float16* __restrict__ K,
                                                     const _Float16* __restrict__ V,
                                                     _Float16* __restrict__ Z) {
    __shared__ float sh[4][3][8][68];   // [wave][Q/K/V][b][d(+pad)]
    int wave = threadIdx.x >> 6;
    int lane = threadIdx.x & 63;
    int idx = blockIdx.x * 4 + wave;    // idx = s*H + h
    int s = idx >> 4;
    int h = idx & 15;

    size_t base = ((size_t)s * B_DIM) * E_DIM + (size_t)h * HD_DIM;
    int lb = lane >> 3;   // 0..7: batch row
    int lc = lane & 7;    // 8-half chunk
    {
        half8 q8 = *(const half8*)(Q + base + (size_t)lb * E_DIM + lc * 8);
        half8 k8 = *(const half8*)(K + base + (size_t)lb * E_DIM + lc * 8);
        half8 v8 = *(const half8*)(V + base + (size_t)lb * E_DIM + lc * 8);
        #pragma unroll
        for (int j = 0; j < 8; ++j) {
            sh[wave][0][lb][lc * 8 + j] = (float)q8[j];
            sh[wave][1][lb][lc * 8 + j] = (float)k8[j];
            sh[wave][2][lb][lc * 8 + j] = (float)v8[j];
        }
    }
    __syncthreads();

    int b = lane >> 3;
    int c = lane & 7;
    float dot = 0.0f;
    #pragma unroll
    for (int d = 0; d < HD_DIM; ++d)
        dot += sh[wave][0][b][d] * sh[wave][1][c][d];
    dot *= 0.125f;   // HD^-0.5

    float m = dot;
    m = fmaxf(m, __shfl_xor(m, 1, 64));
    m = fmaxf(m, __shfl_xor(m, 2, 64));
    m = fmaxf(m, __shfl_xor(m, 4, 64));
    float p = expf(dot - m);
    float l = p;
    l += __shfl_xor(l, 1, 64);
    l += __shfl_xor(l, 2, 64);
    l += __shfl_xor(l, 4, 64);
    float a = p / l;

    int g = c;   // lane owns (b, d = g*8 .. g*8+7)
    float o[8] = {0, 0, 0, 0, 0, 0, 0, 0};
    #pragma unroll
    for (int cc = 0; cc < 8; ++cc) {
        float ac = __shfl(a, b * 8 + cc, 64);
        #pragma unroll
        for (int j = 0; j < 8; ++j)
            o[j] += ac * sh[wave][2][cc][g * 8 + j];
    }
    size_t zbase = (((size_t)b * H_DIM + h) * S_DIM + s) * HD_DIM + g * 8;
    half8 oz;
    #pragma unroll
    for (int j = 0; j < 8; ++j) oz[j] = (_Float16)o[j];
    *(half8*)(Z + zbase) = oz;
}

// ---------------------------------------------------------------------------
// Workspace (peak 344 MB; src2 aliases d_out):
//  [0,24MB)   6 transposed f16 weights
//  region A (256MB): h1z -> Z -> F1 start | Qb | Kb | Vb   (F1 overlays all)
//  h2 (64MB)
// src2 (fp32 residual) lives in d_out: O-proj writes it, LN2/FF2 read it,
// FF2's res-read and C-write of the same element are same-thread (no hazard).
// ---------------------------------------------------------------------------
extern "C" void kernel_launch(void* const* d_in, const int* in_sizes, int n_in,
                              void* d_out, int out_size, void* d_ws, size_t ws_size,
                              hipStream_t stream) {
    const float* src = (const float*)d_in[0];
    const float* Wq  = (const float*)d_in[1];
    const float* bq  = (const float*)d_in[2];
    const float* Wk  = (const float*)d_in[3];
    const float* bk  = (const float*)d_in[4];
    const float* Wv  = (const float*)d_in[5];
    const float* bv  = (const float*)d_in[6];
    const float* Wo  = (const float*)d_in[7];
    const float* bo  = (const float*)d_in[8];
    const float* W1  = (const float*)d_in[9];
    const float* b1  = (const float*)d_in[10];
    const float* W2  = (const float*)d_in[11];
    const float* b2  = (const float*)d_in[12];
    const float* g1  = (const float*)d_in[13];
    const float* be1 = (const float*)d_in[14];
    const float* g2  = (const float*)d_in[15];
    const float* be2 = (const float*)d_in[16];
    float* out = (float*)d_out;

    const size_t NE = (size_t)ROWS * E_DIM;   // 33,554,432
    _Float16* Wqt = (_Float16*)d_ws;
    _Float16* Wkt = Wqt + (size_t)E_DIM * E_DIM;
    _Float16* Wvt = Wkt + (size_t)E_DIM * E_DIM;
    _Float16* Wot = Wvt + (size_t)E_DIM * E_DIM;
    _Float16* W1t = Wot + (size_t)E_DIM * E_DIM;     // [FF][E]
    _Float16* W2t = W1t + (size_t)E_DIM * FF_DIM;    // [E][FF]
    _Float16* h1z = W2t + (size_t)E_DIM * FF_DIM;    // h1 -> Z -> F1 start
    _Float16* Qb  = h1z + NE;
    _Float16* Kb  = Qb + NE;
    _Float16* Vb  = Kb + NE;
    _Float16* h2  = Vb + NE;
    _Float16* F1  = h1z;                              // 4*NE halves
    float*    src2 = out;                             // fp32 residual in d_out

    dim3 blk(256);
    cvt_t_kernel<<<dim3(32, 32), blk, 0, stream>>>(Wq, Wqt, E_DIM, E_DIM);
    cvt_t_kernel<<<dim3(32, 32), blk, 0, stream>>>(Wk, Wkt, E_DIM, E_DIM);
    cvt_t_kernel<<<dim3(32, 32), blk, 0, stream>>>(Wv, Wvt, E_DIM, E_DIM);
    cvt_t_kernel<<<dim3(32, 32), blk, 0, stream>>>(Wo, Wot, E_DIM, E_DIM);
    cvt_t_kernel<<<dim3(128, 32), blk, 0, stream>>>(W1, W1t, E_DIM, FF_DIM);
    cvt_t_kernel<<<dim3(32, 128), blk, 0, stream>>>(W2, W2t, FF_DIM, E_DIM);

    ln16_kernel<<<ROWS, blk, 0, stream>>>(src, g1, be1, h1z);

    dim3 gE(E_DIM / 128, ROWS / 128);    // (8, 256), nwg=2048 (%8==0)
    gemm16_kernel<0, 0, 1><<<gE, blk, 0, stream>>>(h1z, Wqt, bq, nullptr, Qb, E_DIM, E_DIM);
    gemm16_kernel<0, 0, 1><<<gE, blk, 0, stream>>>(h1z, Wkt, bk, nullptr, Kb, E_DIM, E_DIM);
    gemm16_kernel<0, 0, 1><<<gE, blk, 0, stream>>>(h1z, Wvt, bv, nullptr, Vb, E_DIM, E_DIM);

    _Float16* Zb = h1z;   // overwrite h1 (dead after QKV)
    attn16_kernel<<<(S_DIM * H_DIM) / 4, blk, 0, stream>>>(Qb, Kb, Vb, Zb);

    gemm16_kernel<0, 1, 0><<<gE, blk, 0, stream>>>(Zb, Wot, bo, src, src2, E_DIM, E_DIM);

    ln16_kernel<<<ROWS, blk, 0, stream>>>(src2, g2, be2, h2);

    dim3 gF(FF_DIM / 128, ROWS / 128);   // (32, 256), nwg=8192 (%8==0)
    gemm16_kernel<1, 0, 1><<<gF, blk, 0, stream>>>(h2, W1t, b1, nullptr, F1, E_DIM, FF_DIM);
    gemm16_kernel<0, 1, 0><<<gE, blk, 0, stream>>>(F1, W2t, b2, src2, out, FF_DIM, E_DIM);
}